// Round 1
// baseline (858.865 us; speedup 1.0000x reference)
//
#include <hip/hip_runtime.h>
#include <hip/hip_bf16.h>
#include <cstdint>

// Problem constants
#define R_TOT 16384      // BS*LS
#define T_NT  2048       // NTGT
#define DD    128        // D
#define HH    512        // H
#define MC_   20
#define ROWS  8          // rows per block in fused kernel

// Output layout (floats)
#define MASK_OFF 0
#define LOGP_OFF 16384
#define WORD_OFF 32768
#define CHAR_OFF 49152
#define EMB_OFF  376832          // 49152 + 16384*20
#define LOSS_OFF 2473984         // 376832 + 16384*128

// ws layout (floats)
#define X_OFF    0               // 16384*128
#define HDN_OFF  2097152         // 16384*512
#define WT_OFF   10485760        // 2048*128
#define ENT_OFF  10747904        // 2048
#define CNT_OFF  10749952        // 2048

// ---------------- K1: gather embeddings ----------------
__global__ __launch_bounds__(256) void k1_gather(
    const int* __restrict__ inp_word, const int* __restrict__ tgt_ids,
    const float* __restrict__ W, float* __restrict__ x, float* __restrict__ wtgt)
{
    int row = blockIdx.x * 2 + (threadIdx.x >> 7);
    int d = threadIdx.x & 127;
    if (row < R_TOT) {
        int wsrc = inp_word[row];
        x[(size_t)row * DD + d] = W[(size_t)wsrc * DD + d];
    } else {
        int rr = row - R_TOT;
        if (rr < T_NT) {
            int wsrc = tgt_ids[rr];
            wtgt[(size_t)rr * DD + d] = W[(size_t)wsrc * DD + d];
        }
    }
}

// ---------------- K2: hdn = relu(x @ W1 + b1) ----------------
// M=16384, N=512, K=128; 64x64 tile, 256 threads, 4x4 per thread
__global__ __launch_bounds__(256) void k2_hdn(
    const float* __restrict__ x, const float* __restrict__ W1,
    const float* __restrict__ b1, float* __restrict__ hdn)
{
    __shared__ float As[16][64];   // [k][m]
    __shared__ float Bs[16][64];   // [k][n]
    const int t = threadIdx.x;
    const int bm = blockIdx.x * 64;
    const int bn = blockIdx.y * 64;
    const int tx = t & 15, ty = t >> 4;
    float acc[4][4] = {};
    for (int k0 = 0; k0 < DD; k0 += 16) {
        {
            int m = t >> 2, kq = t & 3;
            float4 v = *(const float4*)(x + (size_t)(bm + m) * DD + k0 + kq * 4);
            As[kq * 4 + 0][m] = v.x; As[kq * 4 + 1][m] = v.y;
            As[kq * 4 + 2][m] = v.z; As[kq * 4 + 3][m] = v.w;
        }
        {
            int k = t >> 4, nq = t & 15;
            *(float4*)(&Bs[k][nq * 4]) =
                *(const float4*)(W1 + (size_t)(k0 + k) * HH + bn + nq * 4);
        }
        __syncthreads();
        #pragma unroll
        for (int k = 0; k < 16; ++k) {
            float a[4], b[4];
            #pragma unroll
            for (int i = 0; i < 4; i++) a[i] = As[k][ty * 4 + i];
            #pragma unroll
            for (int j = 0; j < 4; j++) b[j] = Bs[k][tx * 4 + j];
            #pragma unroll
            for (int i = 0; i < 4; i++)
                #pragma unroll
                for (int j = 0; j < 4; j++)
                    acc[i][j] = fmaf(a[i], b[j], acc[i][j]);
        }
        __syncthreads();
    }
    #pragma unroll
    for (int i = 0; i < 4; i++) {
        int m = bm + ty * 4 + i;
        int n = bn + tx * 4;
        float4 v;
        v.x = fmaxf(acc[i][0] + b1[n + 0], 0.f);
        v.y = fmaxf(acc[i][1] + b1[n + 1], 0.f);
        v.z = fmaxf(acc[i][2] + b1[n + 2], 0.f);
        v.w = fmaxf(acc[i][3] + b1[n + 3], 0.f);
        *(float4*)(hdn + (size_t)m * HH + n) = v;
    }
}

// ---------------- K3: fused logits + softmax stats + gumbel + x_emb + outputs ----------------
// One block per 8 rows. 512 threads (8 waves). LDS ~82 KB.
__global__ __launch_bounds__(512) void k3_fused(
    const float* __restrict__ hdn, const float* __restrict__ W2,
    const float* __restrict__ b2, const float* __restrict__ gumbel,
    const int* __restrict__ inp_word, const int* __restrict__ keyword_table,
    const int* __restrict__ tgt_ids, const int* __restrict__ lut,
    const float* __restrict__ x, const float* __restrict__ wtgt,
    float* __restrict__ out, float* __restrict__ entP, float* __restrict__ cntP)
{
    __shared__ float hdnS[ROWS * HH];        // 16 KB; reused as xemb partials in phase D
    __shared__ float logitsS[ROWS * T_NT];   // 64 KB; overwritten with gumbel-softmax numerators
    __shared__ float invs2S[ROWS], entS[ROWS];
    __shared__ int mskS[ROWS], cntS[ROWS];

    const int t = threadIdx.x;
    const int blk = blockIdx.x;
    const int row0 = blk * ROWS;

    // Phase A: stage hdn tile
    {
        const float4* hsrc = (const float4*)(hdn + (size_t)row0 * HH);
        float4* hdst = (float4*)hdnS;
        #pragma unroll
        for (int i = 0; i < (ROWS * HH / 4) / 512; ++i)
            hdst[t + i * 512] = hsrc[t + i * 512];
    }
    __syncthreads();

    // Phase B: logits[8][2048] = hdnS @ W2 + b2   (K=512)
    {
        const int c0 = t * 4;  // each thread owns 4 consecutive cols, all 8 rows
        float acc[ROWS][4];
        #pragma unroll
        for (int r = 0; r < ROWS; r++)
            acc[r][0] = acc[r][1] = acc[r][2] = acc[r][3] = 0.f;
        for (int k = 0; k < HH; k += 4) {
            float4 w0 = *(const float4*)(W2 + (size_t)(k + 0) * T_NT + c0);
            float4 w1 = *(const float4*)(W2 + (size_t)(k + 1) * T_NT + c0);
            float4 w2 = *(const float4*)(W2 + (size_t)(k + 2) * T_NT + c0);
            float4 w3 = *(const float4*)(W2 + (size_t)(k + 3) * T_NT + c0);
            #pragma unroll
            for (int r = 0; r < ROWS; r++) {
                float4 h = *(const float4*)(hdnS + r * HH + k);
                acc[r][0] = fmaf(h.x, w0.x, fmaf(h.y, w1.x, fmaf(h.z, w2.x, fmaf(h.w, w3.x, acc[r][0]))));
                acc[r][1] = fmaf(h.x, w0.y, fmaf(h.y, w1.y, fmaf(h.z, w2.y, fmaf(h.w, w3.y, acc[r][1]))));
                acc[r][2] = fmaf(h.x, w0.z, fmaf(h.y, w1.z, fmaf(h.z, w2.z, fmaf(h.w, w3.z, acc[r][2]))));
                acc[r][3] = fmaf(h.x, w0.w, fmaf(h.y, w1.w, fmaf(h.z, w2.w, fmaf(h.w, w3.w, acc[r][3]))));
            }
        }
        float4 bb = *(const float4*)(b2 + c0);
        #pragma unroll
        for (int r = 0; r < ROWS; r++) {
            float4 v = make_float4(acc[r][0] + bb.x, acc[r][1] + bb.y,
                                   acc[r][2] + bb.z, acc[r][3] + bb.w);
            *(float4*)(logitsS + r * T_NT + c0) = v;
        }
    }
    __syncthreads();

    // Phase C: per-row reductions; wave w handles row w
    {
        const int wid = t >> 6, lane = t & 63;
        const int r = wid;
        const int grow = row0 + r;
        // pass 1: max logit, top-2 of (logit+gumbel) with index
        float m = -1e30f, a1 = -1e30f, a2 = -1e30f;
        int i1 = 0;
        for (int c = lane; c < T_NT; c += 64) {
            float l = logitsS[r * T_NT + c];
            float g = gumbel[(size_t)grow * T_NT + c];
            float a = l + g;
            m = fmaxf(m, l);
            if (a > a1) { a2 = a1; a1 = a; i1 = c; }
            else if (a > a2) a2 = a;
        }
        #pragma unroll
        for (int mask = 1; mask < 64; mask <<= 1) {
            float om = __shfl_xor(m, mask);
            float oa1 = __shfl_xor(a1, mask);
            float oa2 = __shfl_xor(a2, mask);
            int oi1 = __shfl_xor(i1, mask);
            m = fmaxf(m, om);
            if (oa1 > a1 || (oa1 == a1 && oi1 < i1)) {
                a2 = fmaxf(a1, oa2); a1 = oa1; i1 = oi1;
            } else {
                a2 = fmaxf(a2, oa1);
            }
        }
        // pass 2: sums for lse/entropy + gumbel-softmax denom; store numerators
        float sE = 0.f, sEl = 0.f, s2 = 0.f;
        for (int c = lane; c < T_NT; c += 64) {
            float l = logitsS[r * T_NT + c];
            float g = gumbel[(size_t)grow * T_NT + c];
            float e1 = __expf(l - m);
            sE += e1; sEl = fmaf(e1, l, sEl);
            float e2 = __expf((l + g - a1) * 2.0f);   // /TEMP, TEMP=0.5
            s2 += e2;
            logitsS[r * T_NT + c] = e2;
        }
        #pragma unroll
        for (int mask = 1; mask < 64; mask <<= 1) {
            sE += __shfl_xor(sE, mask);
            sEl += __shfl_xor(sEl, mask);
            s2 += __shfl_xor(s2, mask);
        }
        float lse = m + __logf(sE);
        float ent = lse - sEl / sE;
        int w_in = inp_word[grow];
        int msk = keyword_table[w_in] != 0;
        int word = msk ? tgt_ids[i1] : w_in;
        if (lane == 0) {
            out[MASK_OFF + grow] = msk ? 1.0f : 0.0f;
            out[LOGP_OFF + grow] = msk ? m : 0.0f;
            out[WORD_OFF + grow] = (float)word;
            invs2S[r] = 1.0f / s2;
            mskS[r] = msk;
            entS[r] = msk ? ent : 0.0f;
            cntS[r] = msk;
        }
        if (lane < MC_) {
            out[CHAR_OFF + (size_t)grow * MC_ + lane] = (float)lut[(size_t)word * MC_ + lane];
        }
    }
    __syncthreads();

    if (t == 0) {
        float es = 0.f; int cs = 0;
        #pragma unroll
        for (int r = 0; r < ROWS; r++) { es += entS[r]; cs += cntS[r]; }
        entP[blk] = es;
        cntP[blk] = (float)cs;
    }

    // Phase D: x_emb = numer @ wtgt, scale by 1/s2, select vs x
    {
        float* xembS = hdnS;  // reuse: 4 partials * 8 rows * 128 = 4096 floats
        const int d = t & 127;
        const int q = t >> 7;  // 0..3
        float acc[ROWS];
        #pragma unroll
        for (int r = 0; r < ROWS; r++) acc[r] = 0.f;
        const int tt0 = q * (T_NT / 4);
        for (int tt = tt0; tt < tt0 + T_NT / 4; tt += 4) {
            float w0 = wtgt[(size_t)(tt + 0) * DD + d];
            float w1 = wtgt[(size_t)(tt + 1) * DD + d];
            float w2 = wtgt[(size_t)(tt + 2) * DD + d];
            float w3 = wtgt[(size_t)(tt + 3) * DD + d];
            #pragma unroll
            for (int r = 0; r < ROWS; r++) {
                float4 p = *(const float4*)(logitsS + r * T_NT + tt);
                acc[r] = fmaf(p.x, w0, fmaf(p.y, w1, fmaf(p.z, w2, fmaf(p.w, w3, acc[r]))));
            }
        }
        #pragma unroll
        for (int r = 0; r < ROWS; r++)
            xembS[(q * ROWS + r) * DD + d] = acc[r];
    }
    __syncthreads();
    {
        for (int o = t; o < ROWS * DD; o += 512) {
            int r = o >> 7, d = o & 127;
            float v = (hdnS[(0 * ROWS + r) * DD + d] + hdnS[(1 * ROWS + r) * DD + d] +
                       hdnS[(2 * ROWS + r) * DD + d] + hdnS[(3 * ROWS + r) * DD + d]) * invs2S[r];
            int grow = row0 + r;
            float res = mskS[r] ? v : x[(size_t)grow * DD + d];
            out[EMB_OFF + (size_t)grow * DD + d] = res;
        }
    }
}

// ---------------- K4: final loss reduction ----------------
__global__ __launch_bounds__(256) void k4_loss(
    const float* __restrict__ entP, const float* __restrict__ cntP, float* __restrict__ out)
{
    __shared__ float sE[256], sC[256];
    int t = threadIdx.x;
    float e = 0.f, c = 0.f;
    for (int i = t; i < 2048; i += 256) { e += entP[i]; c += cntP[i]; }
    sE[t] = e; sC[t] = c;
    __syncthreads();
    for (int s = 128; s > 0; s >>= 1) {
        if (t < s) { sE[t] += sE[t + s]; sC[t] += sC[t + s]; }
        __syncthreads();
    }
    if (t == 0) {
        float ns = fmaxf(sC[0], 1.0f);
        out[LOSS_OFF] = 0.03f * sE[0] / ns;
    }
}

// ---------------- launch ----------------
extern "C" void kernel_launch(void* const* d_in, const int* in_sizes, int n_in,
                              void* d_out, int out_size, void* d_ws, size_t ws_size,
                              hipStream_t stream) {
    const int* inp_word = (const int*)d_in[0];
    // d_in[1] inp_char, d_in[2] inp_pos: unused by the reference outputs
    const int* keyword_table = (const int*)d_in[3];
    const int* tgt_ids = (const int*)d_in[4];
    const int* lut = (const int*)d_in[5];
    const float* gumbel = (const float*)d_in[6];
    const float* W = (const float*)d_in[7];
    const float* W1 = (const float*)d_in[8];
    const float* b1 = (const float*)d_in[9];
    const float* W2 = (const float*)d_in[10];
    const float* b2 = (const float*)d_in[11];
    float* out = (float*)d_out;

    float* wsf = (float*)d_ws;
    float* x = wsf + X_OFF;
    float* hdn = wsf + HDN_OFF;
    float* wtgt = wsf + WT_OFF;
    float* entP = wsf + ENT_OFF;
    float* cntP = wsf + CNT_OFF;

    k1_gather<<<(R_TOT + T_NT) / 2, 256, 0, stream>>>(inp_word, tgt_ids, W, x, wtgt);
    k2_hdn<<<dim3(R_TOT / 64, HH / 64), 256, 0, stream>>>(x, W1, b1, hdn);
    k3_fused<<<R_TOT / ROWS, 512, 0, stream>>>(hdn, W2, b2, gumbel, inp_word,
                                               keyword_table, tgt_ids, lut, x, wtgt,
                                               out, entP, cntP);
    k4_loss<<<1, 256, 0, stream>>>(entP, cntP, out);
}

// Round 2
// 458.820 us; speedup vs baseline: 1.8719x; 1.8719x over previous
//
#include <hip/hip_runtime.h>
#include <cstdint>

#define R_TOT 16384
#define T_NT  2048
#define DD    128
#define HH    512
#define MC_   20
#define ROWS  16

// Output layout (floats)
#define MASK_OFF 0
#define LOGP_OFF 16384
#define WORD_OFF 32768
#define CHAR_OFF 49152
#define EMB_OFF  376832          // 49152 + 16384*20
#define LOSS_OFF 2473984         // 376832 + 16384*128

// ws layout (float slots)
#define X_OFF     0              // x f32 [16384][128]
#define HDN_OFF   2097152        // hdn f32 [16384][512]
#define HDNB_OFF  10485760       // hdn bf16 ushort[16384*512] (4,194,304 slots)
#define WT_OFF    14680064       // wtgt f32 [2048][128]
#define WTT_OFF   14942208       // wtgtT bf16 ushort[128*2048] (131,072 slots)
#define W2T_OFF   15073280       // W2T f32 [2048][512]
#define W2TB_OFF  16121856       // W2T bf16 ushort[2048*512] (524,288 slots)
#define ENT_OFF   16646144       // 1024
#define CNT_OFF   16647168       // 1024

typedef __attribute__((ext_vector_type(8))) short short8v;
typedef __attribute__((ext_vector_type(4))) float f32x4;
typedef unsigned short ushort_t;

__device__ __forceinline__ ushort_t f2bf(float f) {
    union { float f; unsigned int u; } v; v.f = f;
    unsigned int r = v.u + 0x7FFFu + ((v.u >> 16) & 1u);
    return (ushort_t)(r >> 16);
}

// ---------------- K1: gather embeddings ----------------
__global__ __launch_bounds__(256) void k1_gather(
    const int* __restrict__ inp_word, const int* __restrict__ tgt_ids,
    const float* __restrict__ W, float* __restrict__ x, float* __restrict__ wtgt)
{
    int row = blockIdx.x * 2 + (threadIdx.x >> 7);
    int d = threadIdx.x & 127;
    if (row < R_TOT) {
        int wsrc = inp_word[row];
        x[(size_t)row * DD + d] = W[(size_t)wsrc * DD + d];
    } else {
        int rr = row - R_TOT;
        if (rr < T_NT) {
            int wsrc = tgt_ids[rr];
            wtgt[(size_t)rr * DD + d] = W[(size_t)wsrc * DD + d];
        }
    }
}

// ---------------- K1b: wtgt [2048][128] -> wtgtT bf16 [128][2048] ----------------
__global__ __launch_bounds__(256) void k1b_wtgtT(
    const float* __restrict__ wtgt, ushort_t* __restrict__ wtgtT)
{
    __shared__ float tile[32][33];
    int tb = blockIdx.x * 32, db = blockIdx.y * 32;
    int lx = threadIdx.x & 31, ly = threadIdx.x >> 5;
    #pragma unroll
    for (int i = 0; i < 32; i += 8)
        tile[ly + i][lx] = wtgt[(size_t)(tb + ly + i) * DD + db + lx];
    __syncthreads();
    #pragma unroll
    for (int i = 0; i < 32; i += 8)
        wtgtT[(size_t)(db + ly + i) * T_NT + tb + lx] = f2bf(tile[lx][ly + i]);
}

// ---------------- K0: W2 [512][2048] -> W2T f32+bf16 [2048][512] ----------------
__global__ __launch_bounds__(256) void k0_w2t(
    const float* __restrict__ W2, float* __restrict__ W2Tf, ushort_t* __restrict__ W2Tb)
{
    __shared__ float tile[32][33];
    int cb = blockIdx.x * 32, kb = blockIdx.y * 32;
    int lx = threadIdx.x & 31, ly = threadIdx.x >> 5;
    #pragma unroll
    for (int i = 0; i < 32; i += 8)
        tile[ly + i][lx] = W2[(size_t)(kb + ly + i) * T_NT + cb + lx];
    __syncthreads();
    #pragma unroll
    for (int i = 0; i < 32; i += 8) {
        int c = cb + ly + i, k = kb + lx;
        float v = tile[lx][ly + i];
        W2Tf[(size_t)c * HH + k] = v;
        W2Tb[(size_t)c * HH + k] = f2bf(v);
    }
}

// ---------------- K2: hdn = relu(x @ W1 + b1), fp32 + bf16 outputs ----------------
__global__ __launch_bounds__(256) void k2_hdn(
    const float* __restrict__ x, const float* __restrict__ W1,
    const float* __restrict__ b1, float* __restrict__ hdn, ushort_t* __restrict__ hdnB)
{
    __shared__ float As[16][64];
    __shared__ float Bs[16][64];
    const int t = threadIdx.x;
    const int bm = blockIdx.x * 64;
    const int bn = blockIdx.y * 64;
    const int tx = t & 15, ty = t >> 4;
    float acc[4][4] = {};
    for (int k0 = 0; k0 < DD; k0 += 16) {
        {
            int m = t >> 2, kq = t & 3;
            float4 v = *(const float4*)(x + (size_t)(bm + m) * DD + k0 + kq * 4);
            As[kq * 4 + 0][m] = v.x; As[kq * 4 + 1][m] = v.y;
            As[kq * 4 + 2][m] = v.z; As[kq * 4 + 3][m] = v.w;
        }
        {
            int k = t >> 4, nq = t & 15;
            *(float4*)(&Bs[k][nq * 4]) =
                *(const float4*)(W1 + (size_t)(k0 + k) * HH + bn + nq * 4);
        }
        __syncthreads();
        #pragma unroll
        for (int k = 0; k < 16; ++k) {
            float a[4], b[4];
            #pragma unroll
            for (int i = 0; i < 4; i++) a[i] = As[k][ty * 4 + i];
            #pragma unroll
            for (int j = 0; j < 4; j++) b[j] = Bs[k][tx * 4 + j];
            #pragma unroll
            for (int i = 0; i < 4; i++)
                #pragma unroll
                for (int j = 0; j < 4; j++)
                    acc[i][j] = fmaf(a[i], b[j], acc[i][j]);
        }
        __syncthreads();
    }
    #pragma unroll
    for (int i = 0; i < 4; i++) {
        int m = bm + ty * 4 + i;
        int n = bn + tx * 4;
        float4 v;
        v.x = fmaxf(acc[i][0] + b1[n + 0], 0.f);
        v.y = fmaxf(acc[i][1] + b1[n + 1], 0.f);
        v.z = fmaxf(acc[i][2] + b1[n + 2], 0.f);
        v.w = fmaxf(acc[i][3] + b1[n + 3], 0.f);
        *(float4*)(hdn + (size_t)m * HH + n) = v;
        ushort4 hb;
        hb.x = f2bf(v.x); hb.y = f2bf(v.y); hb.z = f2bf(v.z); hb.w = f2bf(v.w);
        *(ushort4*)(hdnB + (size_t)m * HH + n) = hb;
    }
}

// ---------------- K3: MFMA logits + fused stats + repair + MFMA x_emb ----------------
// 16 rows/block, 512 threads (8 waves). LDS ~148 KB.
__global__ __launch_bounds__(512) void k3_fused(
    const ushort_t* __restrict__ hdnB, const float* __restrict__ hdn,
    const ushort_t* __restrict__ W2Tb, const float* __restrict__ W2Tf,
    const float* __restrict__ b2, const float* __restrict__ gumbel,
    const int* __restrict__ inp_word, const int* __restrict__ keyword_table,
    const int* __restrict__ tgt_ids, const int* __restrict__ lut,
    const float* __restrict__ x, const ushort_t* __restrict__ wtgtT,
    float* __restrict__ out, float* __restrict__ entP, float* __restrict__ cntP)
{
    __shared__ ushort_t hdnS[ROWS * 520];     // padded rows (+8 bf16)
    __shared__ float pS[ROWS * 2052];         // logits -> gumbel-softmax numerators
    __shared__ float invs2S[ROWS], entS[ROWS];
    __shared__ int mskS[ROWS], cntS[ROWS];

    const int t = threadIdx.x;
    const int wid = t >> 6, lane = t & 63;
    const int row0 = blockIdx.x * ROWS;
    const int lrow = lane & 15;    // A-row / B-col / C-col index
    const int kgrp = lane >> 4;    // k-chunk group (8 elems each)

    // Phase A: stage hdn bf16 tile
    {
        int row = t >> 5, seg = t & 31;   // 16 rows x 32 segs x 16 elems
        const uint4* src = (const uint4*)(hdnB + (size_t)(row0 + row) * HH + seg * 16);
        uint4* dst = (uint4*)(hdnS + row * 520 + seg * 16);
        dst[0] = src[0]; dst[1] = src[1];
    }
    __syncthreads();

    // Phase B: logits[16][2048] via MFMA; wave wid -> cols [wid*256, wid*256+256)
    {
        const ushort_t* aptr = hdnS + lrow * 520 + kgrp * 8;
        for (int f = 0; f < 16; ++f) {
            const int bcol = wid * 256 + f * 16 + lrow;
            f32x4 acc = {0.f, 0.f, 0.f, 0.f};
            const ushort_t* bptr = W2Tb + (size_t)bcol * HH + kgrp * 8;
            #pragma unroll
            for (int k0 = 0; k0 < HH; k0 += 32) {
                short8v av = *(const short8v*)(aptr + k0);
                short8v bv = *(const short8v*)(bptr + k0);
                acc = __builtin_amdgcn_mfma_f32_16x16x32_bf16(av, bv, acc, 0, 0, 0);
            }
            float bb = b2[bcol];
            #pragma unroll
            for (int q = 0; q < 4; ++q)
                pS[(kgrp * 4 + q) * 2052 + bcol] = acc[q] + bb;
        }
    }
    __syncthreads();

    // Phase C: per-row stats (single pass over gumbel), top-2 + fp32 repair
    for (int rr = wid; rr < ROWS; rr += 8) {
        const int grow = row0 + rr;
        const float* gg = gumbel + (size_t)grow * T_NT;
        float m = -1e30f, a1 = -1e30f, a2 = -1e30f;
        int i1 = 0, i2 = 0;
        float sE = 0.f, sEl = 0.f, s2 = 0.f;
        for (int c = lane; c < T_NT; c += 64) {
            float l = pS[rr * 2052 + c];
            float g = gg[c];
            m = fmaxf(m, l);
            float e1 = __expf(l);
            sE += e1; sEl = fmaf(e1, l, sEl);
            float a = l + g;
            float p = __expf(2.0f * a);     // /TEMP, TEMP=0.5
            s2 += p;
            pS[rr * 2052 + c] = p;
            if (a > a1) { a2 = a1; i2 = i1; a1 = a; i1 = c; }
            else if (a > a2) { a2 = a; i2 = c; }
        }
        #pragma unroll
        for (int mk = 1; mk < 64; mk <<= 1) {
            m = fmaxf(m, __shfl_xor(m, mk));
            sE += __shfl_xor(sE, mk);
            sEl += __shfl_xor(sEl, mk);
            s2 += __shfl_xor(s2, mk);
            float oa1 = __shfl_xor(a1, mk); int oi1 = __shfl_xor(i1, mk);
            float oa2 = __shfl_xor(a2, mk); int oi2 = __shfl_xor(i2, mk);
            if (oa1 > a1 || (oa1 == a1 && oi1 < i1)) {
                if (a1 > oa2) { a2 = a1; i2 = i1; } else { a2 = oa2; i2 = oi2; }
                a1 = oa1; i1 = oi1;
            } else {
                if (oa1 > a2) { a2 = oa1; i2 = oi1; }
            }
        }
        // exact fp32 repair of the top-2 candidates
        const float* hrow = hdn + (size_t)grow * HH;
        float v1, v2;
        {
            const float* wrow = W2Tf + (size_t)i1 * HH;
            float4 h0 = *(const float4*)(hrow + lane * 8);
            float4 h1 = *(const float4*)(hrow + lane * 8 + 4);
            float4 w0 = *(const float4*)(wrow + lane * 8);
            float4 w1 = *(const float4*)(wrow + lane * 8 + 4);
            float s = h0.x*w0.x + h0.y*w0.y + h0.z*w0.z + h0.w*w0.w
                    + h1.x*w1.x + h1.y*w1.y + h1.z*w1.z + h1.w*w1.w;
            #pragma unroll
            for (int mk = 1; mk < 64; mk <<= 1) s += __shfl_xor(s, mk);
            v1 = s + b2[i1] + gg[i1];
        }
        {
            const float* wrow = W2Tf + (size_t)i2 * HH;
            float4 h0 = *(const float4*)(hrow + lane * 8);
            float4 h1 = *(const float4*)(hrow + lane * 8 + 4);
            float4 w0 = *(const float4*)(wrow + lane * 8);
            float4 w1 = *(const float4*)(wrow + lane * 8 + 4);
            float s = h0.x*w0.x + h0.y*w0.y + h0.z*w0.z + h0.w*w0.w
                    + h1.x*w1.x + h1.y*w1.y + h1.z*w1.z + h1.w*w1.w;
            #pragma unroll
            for (int mk = 1; mk < 64; mk <<= 1) s += __shfl_xor(s, mk);
            v2 = s + b2[i2] + gg[i2];
        }
        int ibest = (v2 > v1 || (v2 == v1 && i2 < i1)) ? i2 : i1;

        int w_in = inp_word[grow];
        int msk = keyword_table[w_in] != 0;
        int word = msk ? tgt_ids[ibest] : w_in;
        if (lane == 0) {
            out[MASK_OFF + grow] = msk ? 1.0f : 0.0f;
            out[LOGP_OFF + grow] = msk ? m : 0.0f;
            out[WORD_OFF + grow] = (float)word;
            invs2S[rr] = 1.0f / s2;
            mskS[rr] = msk;
            entS[rr] = msk ? (__logf(sE) - sEl / sE) : 0.0f;
            cntS[rr] = msk;
        }
        if (lane < MC_)
            out[CHAR_OFF + (size_t)grow * MC_ + lane] = (float)lut[(size_t)word * MC_ + lane];
    }
    __syncthreads();

    if (t == 0) {
        float es = 0.f; int cs = 0;
        #pragma unroll
        for (int r = 0; r < ROWS; r++) { es += entS[r]; cs += cntS[r]; }
        entP[blockIdx.x] = es;
        cntP[blockIdx.x] = (float)cs;
    }

    // Phase D: x_emb = (P @ wtgt) / s2 via MFMA; wave wid -> cols [wid*16, wid*16+16)
    {
        const int dcol = wid * 16 + lrow;
        f32x4 acc = {0.f, 0.f, 0.f, 0.f};
        const ushort_t* bbase = wtgtT + (size_t)dcol * T_NT + kgrp * 8;
        const float* abase = pS + lrow * 2052 + kgrp * 8;
        #pragma unroll 4
        for (int k0 = 0; k0 < T_NT; k0 += 32) {
            const float* ap = abase + k0;
            short8v av;
            #pragma unroll
            for (int j = 0; j < 8; ++j) av[j] = (short)f2bf(ap[j]);
            short8v bv = *(const short8v*)(bbase + k0);
            acc = __builtin_amdgcn_mfma_f32_16x16x32_bf16(av, bv, acc, 0, 0, 0);
        }
        #pragma unroll
        for (int q = 0; q < 4; ++q) {
            int mrow = kgrp * 4 + q;
            int grow = row0 + mrow;
            float val = acc[q] * invs2S[mrow];
            if (!mskS[mrow]) val = x[(size_t)grow * DD + dcol];
            out[EMB_OFF + (size_t)grow * DD + dcol] = val;
        }
    }
}

// ---------------- K4: final loss reduction ----------------
__global__ __launch_bounds__(256) void k4_loss(
    const float* __restrict__ entP, const float* __restrict__ cntP, float* __restrict__ out)
{
    __shared__ float sE[256], sC[256];
    int t = threadIdx.x;
    float e = 0.f, c = 0.f;
    for (int i = t; i < 1024; i += 256) { e += entP[i]; c += cntP[i]; }
    sE[t] = e; sC[t] = c;
    __syncthreads();
    for (int s = 128; s > 0; s >>= 1) {
        if (t < s) { sE[t] += sE[t + s]; sC[t] += sC[t + s]; }
        __syncthreads();
    }
    if (t == 0) {
        float ns = fmaxf(sC[0], 1.0f);
        out[LOSS_OFF] = 0.03f * sE[0] / ns;
    }
}

// ---------------- launch ----------------
extern "C" void kernel_launch(void* const* d_in, const int* in_sizes, int n_in,
                              void* d_out, int out_size, void* d_ws, size_t ws_size,
                              hipStream_t stream) {
    const int* inp_word = (const int*)d_in[0];
    const int* keyword_table = (const int*)d_in[3];
    const int* tgt_ids = (const int*)d_in[4];
    const int* lut = (const int*)d_in[5];
    const float* gumbel = (const float*)d_in[6];
    const float* W = (const float*)d_in[7];
    const float* W1 = (const float*)d_in[8];
    const float* b1 = (const float*)d_in[9];
    const float* W2 = (const float*)d_in[10];
    const float* b2 = (const float*)d_in[11];
    float* out = (float*)d_out;

    float* wsf = (float*)d_ws;
    float* x = wsf + X_OFF;
    float* hdn = wsf + HDN_OFF;
    ushort_t* hdnB = (ushort_t*)(wsf + HDNB_OFF);
    float* wtgt = wsf + WT_OFF;
    ushort_t* wtgtT = (ushort_t*)(wsf + WTT_OFF);
    float* W2Tf = wsf + W2T_OFF;
    ushort_t* W2Tb = (ushort_t*)(wsf + W2TB_OFF);
    float* entP = wsf + ENT_OFF;
    float* cntP = wsf + CNT_OFF;

    k1_gather<<<(R_TOT + T_NT) / 2, 256, 0, stream>>>(inp_word, tgt_ids, W, x, wtgt);
    k1b_wtgtT<<<dim3(T_NT / 32, DD / 32), 256, 0, stream>>>(wtgt, wtgtT);
    k0_w2t<<<dim3(T_NT / 32, HH / 32), 256, 0, stream>>>(W2, W2Tf, W2Tb);
    k2_hdn<<<dim3(R_TOT / 64, HH / 64), 256, 0, stream>>>(x, W1, b1, hdn, hdnB);
    k3_fused<<<R_TOT / ROWS, 512, 0, stream>>>(hdnB, hdn, W2Tb, W2Tf, b2, gumbel,
                                               inp_word, keyword_table, tgt_ids, lut,
                                               x, wtgtT, out, entP, cntP);
    k4_loss<<<1, 256, 0, stream>>>(entP, cntP, out);
}

// Round 3
// 219.480 us; speedup vs baseline: 3.9132x; 2.0905x over previous
//
#include <hip/hip_runtime.h>
#include <cstdint>

#define R_TOT 16384
#define T_NT  2048
#define DD    128
#define HH    512
#define MC_   20
#define BR    32          // rows per block in k3
#define STEPS 64          // 2048 / 32 cols
#define NBLK  (R_TOT / BR)   // 512

// Output layout (floats)
#define MASK_OFF 0
#define LOGP_OFF 16384
#define WORD_OFF 32768
#define CHAR_OFF 49152
#define EMB_OFF  376832          // 49152 + 16384*20
#define LOSS_OFF 2473984         // 376832 + 16384*128

// ws layout (float slots)
#define X_OFF     0              // x f32 [16384][128]
#define HDN_OFF   2097152        // hdn f32 [16384][512]
#define HDNB_OFF  10485760       // hdn bf16 ushort[16384*512]
#define WT_OFF    14680064       // wtgt f32 [2048][128]
#define WTT_OFF   14942208       // wtgtT bf16 ushort[128*2048]
#define W2T_OFF   15073280       // W2T f32 [2048][512]
#define W2TB_OFF  16121856       // W2T bf16 ushort[2048*512]
#define ENT_OFF   16646144       // 512
#define CNT_OFF   16647168       // 512

typedef __attribute__((ext_vector_type(8))) short short8v;
typedef __attribute__((ext_vector_type(4))) float f32x4;
typedef unsigned short ushort_t;

__device__ __forceinline__ ushort_t f2bf(float f) {
    union { float f; unsigned int u; } v; v.f = f;
    unsigned int r = v.u + 0x7FFFu + ((v.u >> 16) & 1u);
    return (ushort_t)(r >> 16);
}

__device__ __forceinline__ void stage16(const ushort_t* gsrc, ushort_t* ldst) {
    __builtin_amdgcn_global_load_lds(
        (const __attribute__((address_space(1))) unsigned int*)gsrc,
        (__attribute__((address_space(3))) unsigned int*)ldst, 16, 0, 0);
}

// ---------------- K1: gather embeddings ----------------
__global__ __launch_bounds__(256) void k1_gather(
    const int* __restrict__ inp_word, const int* __restrict__ tgt_ids,
    const float* __restrict__ W, float* __restrict__ x, float* __restrict__ wtgt)
{
    int row = blockIdx.x * 2 + (threadIdx.x >> 7);
    int d = threadIdx.x & 127;
    if (row < R_TOT) {
        int wsrc = inp_word[row];
        x[(size_t)row * DD + d] = W[(size_t)wsrc * DD + d];
    } else {
        int rr = row - R_TOT;
        if (rr < T_NT) {
            int wsrc = tgt_ids[rr];
            wtgt[(size_t)rr * DD + d] = W[(size_t)wsrc * DD + d];
        }
    }
}

// ---------------- K1b: wtgt [2048][128] -> wtgtT bf16 [128][2048] ----------------
__global__ __launch_bounds__(256) void k1b_wtgtT(
    const float* __restrict__ wtgt, ushort_t* __restrict__ wtgtT)
{
    __shared__ float tile[32][33];
    int tb = blockIdx.x * 32, db = blockIdx.y * 32;
    int lx = threadIdx.x & 31, ly = threadIdx.x >> 5;
    #pragma unroll
    for (int i = 0; i < 32; i += 8)
        tile[ly + i][lx] = wtgt[(size_t)(tb + ly + i) * DD + db + lx];
    __syncthreads();
    #pragma unroll
    for (int i = 0; i < 32; i += 8)
        wtgtT[(size_t)(db + ly + i) * T_NT + tb + lx] = f2bf(tile[lx][ly + i]);
}

// ---------------- K0: W2 [512][2048] -> W2T f32+bf16 [2048][512] ----------------
__global__ __launch_bounds__(256) void k0_w2t(
    const float* __restrict__ W2, float* __restrict__ W2Tf, ushort_t* __restrict__ W2Tb)
{
    __shared__ float tile[32][33];
    int cb = blockIdx.x * 32, kb = blockIdx.y * 32;
    int lx = threadIdx.x & 31, ly = threadIdx.x >> 5;
    #pragma unroll
    for (int i = 0; i < 32; i += 8)
        tile[ly + i][lx] = W2[(size_t)(kb + ly + i) * T_NT + cb + lx];
    __syncthreads();
    #pragma unroll
    for (int i = 0; i < 32; i += 8) {
        int c = cb + ly + i, k = kb + lx;
        float v = tile[lx][ly + i];
        W2Tf[(size_t)c * HH + k] = v;
        W2Tb[(size_t)c * HH + k] = f2bf(v);
    }
}

// ---------------- K2: hdn = relu(x @ W1 + b1), fp32 + bf16 outputs ----------------
__global__ __launch_bounds__(256) void k2_hdn(
    const float* __restrict__ x, const float* __restrict__ W1,
    const float* __restrict__ b1, float* __restrict__ hdn, ushort_t* __restrict__ hdnB)
{
    __shared__ float As[16][64];
    __shared__ float Bs[16][64];
    const int t = threadIdx.x;
    const int bm = blockIdx.x * 64;
    const int bn = blockIdx.y * 64;
    const int tx = t & 15, ty = t >> 4;
    float acc[4][4] = {};
    for (int k0 = 0; k0 < DD; k0 += 16) {
        {
            int m = t >> 2, kq = t & 3;
            float4 v = *(const float4*)(x + (size_t)(bm + m) * DD + k0 + kq * 4);
            As[kq * 4 + 0][m] = v.x; As[kq * 4 + 1][m] = v.y;
            As[kq * 4 + 2][m] = v.z; As[kq * 4 + 3][m] = v.w;
        }
        {
            int k = t >> 4, nq = t & 15;
            *(float4*)(&Bs[k][nq * 4]) =
                *(const float4*)(W1 + (size_t)(k0 + k) * HH + bn + nq * 4);
        }
        __syncthreads();
        #pragma unroll
        for (int k = 0; k < 16; ++k) {
            float a[4], b[4];
            #pragma unroll
            for (int i = 0; i < 4; i++) a[i] = As[k][ty * 4 + i];
            #pragma unroll
            for (int j = 0; j < 4; j++) b[j] = Bs[k][tx * 4 + j];
            #pragma unroll
            for (int i = 0; i < 4; i++)
                #pragma unroll
                for (int j = 0; j < 4; j++)
                    acc[i][j] = fmaf(a[i], b[j], acc[i][j]);
        }
        __syncthreads();
    }
    #pragma unroll
    for (int i = 0; i < 4; i++) {
        int m = bm + ty * 4 + i;
        int n = bn + tx * 4;
        float4 v;
        v.x = fmaxf(acc[i][0] + b1[n + 0], 0.f);
        v.y = fmaxf(acc[i][1] + b1[n + 1], 0.f);
        v.z = fmaxf(acc[i][2] + b1[n + 2], 0.f);
        v.w = fmaxf(acc[i][3] + b1[n + 3], 0.f);
        *(float4*)(hdn + (size_t)m * HH + n) = v;
        ushort4 hb;
        hb.x = f2bf(v.x); hb.y = f2bf(v.y); hb.z = f2bf(v.z); hb.w = f2bf(v.w);
        *(ushort4*)(hdnB + (size_t)m * HH + n) = hb;
    }
}

// ---------------- K3: streaming fused kernel ----------------
// 512 blocks x 32 rows, 4 waves = 2 Mgroups(16 rows) x 2 Cgroups.
// Per step (32 cols): S=MFMA(A_regs, W2T_lds) -> stats/top2/P in regs -> P_lds -> PV MFMA.
__global__ __launch_bounds__(256) void k3_fused(
    const ushort_t* __restrict__ hdnB, const float* __restrict__ hdn,
    const ushort_t* __restrict__ W2Tb, const float* __restrict__ W2Tf,
    const float* __restrict__ b2, const float* __restrict__ gumbel,
    const int* __restrict__ inp_word, const int* __restrict__ keyword_table,
    const int* __restrict__ tgt_ids, const int* __restrict__ lut,
    const float* __restrict__ x, const ushort_t* __restrict__ wtgtT,
    float* __restrict__ out, float* __restrict__ entP, float* __restrict__ cntP)
{
    __shared__ ushort_t wS[2][16384];        // 2 x 32KB staged W2T tiles (swizzled)
    __shared__ float pS[2 * 2 * 16 * 36];    // [Mgrp][parity][16 rows][36] P tiles
    __shared__ float statC1[2 * 16 * 8];     // C1 partial stats
    __shared__ int   candS[BR * 2];
    __shared__ float invs2S[BR], entS[BR];
    __shared__ int   mskS[BR];

    const int t = threadIdx.x;
    const int wid = t >> 6, lane = t & 63;
    const int Mgrp = wid >> 1, Cgrp = wid & 1;
    const int lrow = lane & 15, kgrp = lane >> 4;
    const int row0 = blockIdx.x * BR;
    const int rowA = row0 + Mgrp * 16 + lrow;      // this lane's A row
    const int c_local = Cgrp * 16 + lrow;          // col within 32-col tile

    // ---- A fragments: full K in registers (64 VGPRs) ----
    short8v av[16];
    #pragma unroll
    for (int ks = 0; ks < 16; ++ks)
        av[ks] = *(const short8v*)(hdnB + (size_t)rowA * HH + ks * 32 + kgrp * 8);

    // ---- per-lane stats (4 rows: kgrp*4+q) ----
    float m_[4], sE_[4], sEl_[4], s2_[4], a1_[4], a2_[4];
    int i1_[4], i2_[4];
    #pragma unroll
    for (int q = 0; q < 4; ++q) {
        m_[q] = -1e30f; sE_[q] = 0.f; sEl_[q] = 0.f; s2_[q] = 0.f;
        a1_[q] = -1e30f; a2_[q] = -1e30f; i1_[q] = 0; i2_[q] = 0;
    }
    f32x4 accpv[4];
    #pragma unroll
    for (int df = 0; df < 4; ++df) accpv[df] = (f32x4){0.f, 0.f, 0.f, 0.f};

    // ---- staging helper: wave wid stages slots [wid*512, wid*512+512) of 2048 ----
    // slot s: c = s>>6, kc = s&63; contents = W2Tb[col0+c][ (kc^(c&7))*8 .. +8 ]
    auto stage_tile = [&](int buf, int s_step) {
        const int col0 = s_step * 32;
        #pragma unroll
        for (int i = 0; i < 8; ++i) {
            int slot = wid * 512 + i * 64 + lane;
            int c = slot >> 6, kc = slot & 63;
            const ushort_t* gsrc = W2Tb + (size_t)(col0 + c) * HH + ((kc ^ (c & 7)) << 3);
            stage16(gsrc, &wS[buf][(size_t)(wid * 512 + i * 64) * 8]);
        }
    };

    stage_tile(0, 0);
    __syncthreads();

    const int dbase = Cgrp * 64 + lrow;            // d-col base for PV (lrow within frag)

    for (int s = 0; s < STEPS; ++s) {
        const int buf = s & 1, par = s & 1;
        const int col = s * 32 + c_local;          // this lane's logit column

        // -- early loads: gumbel (4), b2 (1), PV-B frags (4) -- issued BEFORE staging
        float g4[4];
        #pragma unroll
        for (int q = 0; q < 4; ++q)
            g4[q] = gumbel[(size_t)(row0 + Mgrp * 16 + kgrp * 4 + q) * T_NT + col];
        float b2v = b2[col];
        short8v bvf[4];
        #pragma unroll
        for (int df = 0; df < 4; ++df)
            bvf[df] = *(const short8v*)(wtgtT + (size_t)(dbase + df * 16) * T_NT + s * 32 + kgrp * 8);

        // -- prefetch next W2T tile --
        if (s + 1 < STEPS) stage_tile(buf ^ 1, s + 1);

        // -- S tile: 16-step MFMA chain, B from swizzled LDS --
        f32x4 acc = (f32x4){0.f, 0.f, 0.f, 0.f};
        #pragma unroll
        for (int ks = 0; ks < 16; ++ks) {
            int kc = ks * 4 + kgrp;
            const short8v bv = *(const short8v*)&wS[buf][c_local * 512 + ((kc ^ (c_local & 7)) << 3)];
            acc = __builtin_amdgcn_mfma_f32_16x16x32_bf16(av[ks], bv, acc, 0, 0, 0);
        }

        // -- P processing: stats + top2 + write P to LDS --
        float* pT = &pS[(Mgrp * 2 + par) * 576];
        #pragma unroll
        for (int q = 0; q < 4; ++q) {
            float l = acc[q] + b2v;
            m_[q] = fmaxf(m_[q], l);
            float e1 = __expf(l);
            sE_[q] += e1; sEl_[q] = fmaf(e1, l, sEl_[q]);
            float a = l + g4[q];
            float p = __expf(2.0f * a);
            s2_[q] += p;
            if (a > a1_[q]) { a2_[q] = a1_[q]; i2_[q] = i1_[q]; a1_[q] = a; i1_[q] = col; }
            else if (a > a2_[q]) { a2_[q] = a; i2_[q] = col; }
            pT[(kgrp * 4 + q) * 36 + c_local] = p;
        }

        __syncthreads();   // staging drained, P visible

        // -- PV: x_emb accumulate; A = P rows (this Mgrp), B = wtgt d-half (this Cgrp) --
        {
            const float* pr = &pS[(Mgrp * 2 + par) * 576 + lrow * 36 + kgrp * 8];
            float4 pa = *(const float4*)(pr);
            float4 pb = *(const float4*)(pr + 4);
            short8v pav;
            pav[0] = (short)f2bf(pa.x); pav[1] = (short)f2bf(pa.y);
            pav[2] = (short)f2bf(pa.z); pav[3] = (short)f2bf(pa.w);
            pav[4] = (short)f2bf(pb.x); pav[5] = (short)f2bf(pb.y);
            pav[6] = (short)f2bf(pb.z); pav[7] = (short)f2bf(pb.w);
            #pragma unroll
            for (int df = 0; df < 4; ++df)
                accpv[df] = __builtin_amdgcn_mfma_f32_16x16x32_bf16(pav, bvf[df], accpv[df], 0, 0, 0);
        }
    }

    // ---- in-wave reduction over lrow (xor 1,2,4,8) ----
    #pragma unroll
    for (int q = 0; q < 4; ++q) {
        #pragma unroll
        for (int mk = 1; mk < 16; mk <<= 1) {
            m_[q] = fmaxf(m_[q], __shfl_xor(m_[q], mk));
            sE_[q] += __shfl_xor(sE_[q], mk);
            sEl_[q] += __shfl_xor(sEl_[q], mk);
            s2_[q] += __shfl_xor(s2_[q], mk);
            float ob1 = __shfl_xor(a1_[q], mk); int oj1 = __shfl_xor(i1_[q], mk);
            float ob2 = __shfl_xor(a2_[q], mk); int oj2 = __shfl_xor(i2_[q], mk);
            if (ob1 > a1_[q] || (ob1 == a1_[q] && oj1 < i1_[q])) {
                if (a1_[q] > ob2 || (a1_[q] == ob2 && i1_[q] < oj2)) { a2_[q] = a1_[q]; i2_[q] = i1_[q]; }
                else { a2_[q] = ob2; i2_[q] = oj2; }
                a1_[q] = ob1; i1_[q] = oj1;
            } else {
                if (ob1 > a2_[q]) { a2_[q] = ob1; i2_[q] = oj1; }
            }
        }
    }

    // ---- cross-C merge via LDS ----
    if (Cgrp == 1 && lrow == 0) {
        #pragma unroll
        for (int q = 0; q < 4; ++q) {
            int r = kgrp * 4 + q;
            float* st = &statC1[(Mgrp * 16 + r) * 8];
            st[0] = m_[q]; st[1] = sE_[q]; st[2] = sEl_[q]; st[3] = s2_[q];
            st[4] = a1_[q]; st[5] = __int_as_float(i1_[q]);
            st[6] = a2_[q]; st[7] = __int_as_float(i2_[q]);
        }
    }
    __syncthreads();

    if (Cgrp == 0) {
        #pragma unroll
        for (int q = 0; q < 4; ++q) {
            int r = kgrp * 4 + q;
            const float* st = &statC1[(Mgrp * 16 + r) * 8];
            float bm = st[0], bsE = st[1], bsEl = st[2], bs2 = st[3];
            float b1v = st[4]; int j1 = __float_as_int(st[5]);
            float b2c = st[6]; int j2 = __float_as_int(st[7]);
            float m = fmaxf(m_[q], bm);
            float sE = sE_[q] + bsE, sEl = sEl_[q] + bsEl, s2 = s2_[q] + bs2;
            float a1 = a1_[q], a2 = a2_[q]; int i1 = i1_[q], i2 = i2_[q];
            if (b1v > a1 || (b1v == a1 && j1 < i1)) {
                if (a1 > b2c || (a1 == b2c && i1 < j2)) { a2 = a1; i2 = i1; }
                else { a2 = b2c; i2 = j2; }
                a1 = b1v; i1 = j1;
            } else {
                if (b1v > a2) { a2 = b1v; i2 = j1; }
            }
            if (lrow == 0) {
                int grow = row0 + Mgrp * 16 + r;
                int w_in = inp_word[grow];
                int msk = keyword_table[w_in] != 0;
                out[MASK_OFF + grow] = msk ? 1.0f : 0.0f;
                out[LOGP_OFF + grow] = msk ? m : 0.0f;
                invs2S[Mgrp * 16 + r] = 1.0f / s2;
                mskS[Mgrp * 16 + r] = msk;
                entS[Mgrp * 16 + r] = msk ? (__logf(sE) - sEl / sE) : 0.0f;
                candS[(Mgrp * 16 + r) * 2 + 0] = i1;
                candS[(Mgrp * 16 + r) * 2 + 1] = i2;
            }
        }
    }
    __syncthreads();

    // ---- x_emb epilogue: scale + select + store ----
    #pragma unroll
    for (int df = 0; df < 4; ++df) {
        #pragma unroll
        for (int q = 0; q < 4; ++q) {
            int rl = Mgrp * 16 + kgrp * 4 + q;
            int grow = row0 + rl;
            int d = dbase + df * 16;
            float val = accpv[df][q] * invs2S[rl];
            if (!mskS[rl]) val = x[(size_t)grow * DD + d];
            out[EMB_OFF + (size_t)grow * DD + d] = val;
        }
    }

    // ---- repair + word/char outputs: wave wid handles rows [wid*8, wid*8+8) ----
    for (int rr = wid * 8; rr < wid * 8 + 8; ++rr) {
        int grow = row0 + rr;
        int i1 = candS[rr * 2 + 0], i2 = candS[rr * 2 + 1];
        const float* hrow = hdn + (size_t)grow * HH;
        float4 h0 = *(const float4*)(hrow + lane * 8);
        float4 h1 = *(const float4*)(hrow + lane * 8 + 4);
        float v1, v2;
        {
            const float* wrow = W2Tf + (size_t)i1 * HH;
            float4 w0 = *(const float4*)(wrow + lane * 8);
            float4 w1 = *(const float4*)(wrow + lane * 8 + 4);
            float sdot = h0.x*w0.x + h0.y*w0.y + h0.z*w0.z + h0.w*w0.w
                       + h1.x*w1.x + h1.y*w1.y + h1.z*w1.z + h1.w*w1.w;
            #pragma unroll
            for (int mk = 1; mk < 64; mk <<= 1) sdot += __shfl_xor(sdot, mk);
            v1 = sdot + b2[i1] + gumbel[(size_t)grow * T_NT + i1];
        }
        {
            const float* wrow = W2Tf + (size_t)i2 * HH;
            float4 w0 = *(const float4*)(wrow + lane * 8);
            float4 w1 = *(const float4*)(wrow + lane * 8 + 4);
            float sdot = h0.x*w0.x + h0.y*w0.y + h0.z*w0.z + h0.w*w0.w
                       + h1.x*w1.x + h1.y*w1.y + h1.z*w1.z + h1.w*w1.w;
            #pragma unroll
            for (int mk = 1; mk < 64; mk <<= 1) sdot += __shfl_xor(sdot, mk);
            v2 = sdot + b2[i2] + gumbel[(size_t)grow * T_NT + i2];
        }
        int ibest = (v2 > v1 || (v2 == v1 && i2 < i1)) ? i2 : i1;
        int w_in = inp_word[grow];
        int msk = mskS[rr];
        int word = msk ? tgt_ids[ibest] : w_in;
        if (lane == 0) out[WORD_OFF + grow] = (float)word;
        if (lane < MC_)
            out[CHAR_OFF + (size_t)grow * MC_ + lane] = (float)lut[(size_t)word * MC_ + lane];
    }

    if (t == 0) {
        float es = 0.f; int cs = 0;
        #pragma unroll
        for (int r = 0; r < BR; r++) { es += entS[r]; cs += mskS[r]; }
        entP[blockIdx.x] = es;
        cntP[blockIdx.x] = (float)cs;
    }
}

// ---------------- K4: final loss reduction ----------------
__global__ __launch_bounds__(256) void k4_loss(
    const float* __restrict__ entP, const float* __restrict__ cntP, float* __restrict__ out)
{
    __shared__ float sE[256], sC[256];
    int t = threadIdx.x;
    float e = 0.f, c = 0.f;
    for (int i = t; i < NBLK; i += 256) { e += entP[i]; c += cntP[i]; }
    sE[t] = e; sC[t] = c;
    __syncthreads();
    for (int s = 128; s > 0; s >>= 1) {
        if (t < s) { sE[t] += sE[t + s]; sC[t] += sC[t + s]; }
        __syncthreads();
    }
    if (t == 0) {
        float ns = fmaxf(sC[0], 1.0f);
        out[LOSS_OFF] = 0.03f * sE[0] / ns;
    }
}

// ---------------- launch ----------------
extern "C" void kernel_launch(void* const* d_in, const int* in_sizes, int n_in,
                              void* d_out, int out_size, void* d_ws, size_t ws_size,
                              hipStream_t stream) {
    const int* inp_word = (const int*)d_in[0];
    const int* keyword_table = (const int*)d_in[3];
    const int* tgt_ids = (const int*)d_in[4];
    const int* lut = (const int*)d_in[5];
    const float* gumbel = (const float*)d_in[6];
    const float* W = (const float*)d_in[7];
    const float* W1 = (const float*)d_in[8];
    const float* b1 = (const float*)d_in[9];
    const float* W2 = (const float*)d_in[10];
    const float* b2 = (const float*)d_in[11];
    float* out = (float*)d_out;

    float* wsf = (float*)d_ws;
    float* x = wsf + X_OFF;
    float* hdn = wsf + HDN_OFF;
    ushort_t* hdnB = (ushort_t*)(wsf + HDNB_OFF);
    float* wtgt = wsf + WT_OFF;
    ushort_t* wtgtT = (ushort_t*)(wsf + WTT_OFF);
    float* W2Tf = wsf + W2T_OFF;
    ushort_t* W2Tb = (ushort_t*)(wsf + W2TB_OFF);
    float* entP = wsf + ENT_OFF;
    float* cntP = wsf + CNT_OFF;

    k1_gather<<<(R_TOT + T_NT) / 2, 256, 0, stream>>>(inp_word, tgt_ids, W, x, wtgt);
    k1b_wtgtT<<<dim3(T_NT / 32, DD / 32), 256, 0, stream>>>(wtgt, wtgtT);
    k0_w2t<<<dim3(T_NT / 32, HH / 32), 256, 0, stream>>>(W2, W2Tf, W2Tb);
    k2_hdn<<<dim3(R_TOT / 64, HH / 64), 256, 0, stream>>>(x, W1, b1, hdn, hdnB);
    k3_fused<<<NBLK, 256, 0, stream>>>(hdnB, hdn, W2Tb, W2Tf, b2, gumbel,
                                       inp_word, keyword_table, tgt_ids, lut,
                                       x, wtgtT, out, entP, cntP);
    k4_loss<<<1, 256, 0, stream>>>(entP, cntP, out);
}